// Round 1
// baseline (912.532 us; speedup 1.0000x reference)
//
#include <hip/hip_runtime.h>
#include <math.h>
#include <stdint.h>

constexpr int N   = 50000;
constexpr int E   = 800000;
constexpr int IN  = 128;
constexpr int H   = 256;
constexpr int OUT = 10;
constexpr int G   = 512;

// ---------------- CSR build ----------------

__global__ void deg_kernel(const int* __restrict__ dst, int* __restrict__ deg) {
  int e = blockIdx.x * blockDim.x + threadIdx.x;
  if (e < E) atomicAdd(&deg[dst[e]], 1);
}

__global__ __launch_bounds__(1024) void scan_kernel(const int* __restrict__ deg,
                                                    int* __restrict__ rowptr,
                                                    int* __restrict__ cur) {
  __shared__ int buf[1024];
  __shared__ int chunk_off;
  int t = threadIdx.x;
  if (t == 0) chunk_off = 0;
  __syncthreads();
  for (int base = 0; base < N; base += 1024) {
    int v = (base + t < N) ? deg[base + t] : 0;
    buf[t] = v;
    __syncthreads();
    for (int off = 1; off < 1024; off <<= 1) {
      int add = (t >= off) ? buf[t - off] : 0;
      __syncthreads();
      buf[t] += add;
      __syncthreads();
    }
    int excl = buf[t] - v;      // exclusive scan within chunk
    int o = chunk_off;
    if (base + t < N) { rowptr[base + t] = o + excl; cur[base + t] = o + excl; }
    __syncthreads();
    if (t == 0) chunk_off += buf[1023];
    __syncthreads();
  }
  if (t == 0) rowptr[N] = chunk_off;   // == E
}

__global__ void fill_kernel(const int* __restrict__ src, const int* __restrict__ dst,
                            int* __restrict__ cur, int* __restrict__ csre) {
  int e = blockIdx.x * blockDim.x + threadIdx.x;
  if (e >= E) return;
  int d = dst[e];
  int pos = atomicAdd(&cur[d], 1);
  csre[pos] = src[e];
}

// ---------------- gather aggregation: out[i] = (1+eps)*in[i] + sum_{j in N(i)} in[j] ----------------

template <int D>
__global__ void agg_kernel(const float* __restrict__ in, const int* __restrict__ rowptr,
                           const int* __restrict__ csre, const float* __restrict__ epsp,
                           float* __restrict__ out) {
  int i = blockIdx.x;
  int t = threadIdx.x;               // blockDim == D
  int s = rowptr[i], e = rowptr[i + 1];
  float acc = 0.f;
  for (int j = s; j < e; ++j) {
    int nbr = csre[j];
    acc += in[(size_t)nbr * D + t];
  }
  out[(size_t)i * D + t] = (1.0f + epsp[0]) * in[(size_t)i * D + t] + acc;
}

// ---------------- fp32 register-tiled GEMM: out[N][256] = act(A[N][K] @ W[K][256] + b) ----------------
// block: 256 threads, 64x64 output tile, each thread 4x4, BK=16.

template <int K, bool RELU>
__global__ __launch_bounds__(256) void gemm_kernel(const float* __restrict__ A,
                                                   const float* __restrict__ W,
                                                   const float* __restrict__ bias,
                                                   float* __restrict__ out, int Nrows) {
  constexpr int M = 256;
  __shared__ __align__(16) float As[16][64];  // [k][row]
  __shared__ __align__(16) float Bs[16][64];  // [k][col]
  const int tid = threadIdx.x;
  const int r0 = blockIdx.x * 64;
  const int c0 = blockIdx.y * 64;
  const int tm = tid >> 4;           // 0..15
  const int tn = tid & 15;           // 0..15
  const int arow = tid >> 2;         // 0..63
  const int akq  = (tid & 3) * 4;    // 0,4,8,12
  const int bk   = tid >> 4;         // 0..15
  const int bc   = (tid & 15) * 4;   // 0..60

  float acc[4][4] = {};

  for (int k0 = 0; k0 < K; k0 += 16) {
    float4 av = make_float4(0.f, 0.f, 0.f, 0.f);
    int grow = r0 + arow;
    if (grow < Nrows) av = *(const float4*)(A + (size_t)grow * K + k0 + akq);
    As[akq + 0][arow] = av.x;
    As[akq + 1][arow] = av.y;
    As[akq + 2][arow] = av.z;
    As[akq + 3][arow] = av.w;
    *(float4*)&Bs[bk][bc] = *(const float4*)(W + (size_t)(k0 + bk) * M + c0 + bc);
    __syncthreads();
#pragma unroll
    for (int kk = 0; kk < 16; ++kk) {
      const float4 a4 = *(const float4*)&As[kk][tm * 4];
      const float4 b4 = *(const float4*)&Bs[kk][tn * 4];
      const float a[4] = {a4.x, a4.y, a4.z, a4.w};
      const float b[4] = {b4.x, b4.y, b4.z, b4.w};
#pragma unroll
      for (int i = 0; i < 4; ++i)
#pragma unroll
        for (int j = 0; j < 4; ++j) acc[i][j] = fmaf(a[i], b[j], acc[i][j]);
    }
    __syncthreads();
  }

  const float4 bias4 = *(const float4*)(bias + c0 + tn * 4);
  const float bv[4] = {bias4.x, bias4.y, bias4.z, bias4.w};
#pragma unroll
  for (int i = 0; i < 4; ++i) {
    int grow = r0 + tm * 4 + i;
    if (grow >= Nrows) continue;
    float4 o;
    o.x = acc[i][0] + bv[0];
    o.y = acc[i][1] + bv[1];
    o.z = acc[i][2] + bv[2];
    o.w = acc[i][3] + bv[3];
    if (RELU) {
      o.x = fmaxf(o.x, 0.f); o.y = fmaxf(o.y, 0.f);
      o.z = fmaxf(o.z, 0.f); o.w = fmaxf(o.w, 0.f);
    }
    *(float4*)(out + (size_t)grow * M + c0 + tn * 4) = o;
  }
}

// ---------------- per-graph mean pool (batch is sorted) ----------------

__global__ void pool_kernel(const float* __restrict__ h2, const int* __restrict__ batch,
                            float* __restrict__ pooled) {
  int g = blockIdx.x;
  int t = threadIdx.x;  // 256
  int lo = 0, hi = N;
  while (lo < hi) { int m = (lo + hi) >> 1; if (batch[m] < g) lo = m + 1; else hi = m; }
  int s = lo;
  lo = 0; hi = N;
  while (lo < hi) { int m = (lo + hi) >> 1; if (batch[m] < g + 1) lo = m + 1; else hi = m; }
  int e = lo;
  float acc = 0.f;
  for (int n = s; n < e; ++n) acc += h2[(size_t)n * H + t];
  pooled[(size_t)g * H + t] = acc / fmaxf((float)(e - s), 1.0f);
}

// ---------------- final linear + log_softmax ----------------

__global__ void final_kernel(const float* __restrict__ pooled, const float* __restrict__ Wlin,
                             const float* __restrict__ blin, float* __restrict__ out) {
  int g = blockIdx.x;
  int t = threadIdx.x;  // 64
  __shared__ float sp[H];
  __shared__ float logits[OUT];
  for (int i = t; i < H; i += 64) sp[i] = pooled[(size_t)g * H + i];
  __syncthreads();
  if (t < OUT) {
    float acc = blin[t];
    for (int k = 0; k < H; ++k) acc = fmaf(sp[k], Wlin[k * OUT + t], acc);
    logits[t] = acc;
  }
  __syncthreads();
  if (t == 0) {
    float m = -INFINITY;
    for (int j = 0; j < OUT; ++j) m = fmaxf(m, logits[j]);
    float s = 0.f;
    for (int j = 0; j < OUT; ++j) s += expf(logits[j] - m);
    float ls = logf(s);
    for (int j = 0; j < OUT; ++j) out[(size_t)g * OUT + j] = logits[j] - m - ls;
  }
}

// ---------------- launch ----------------

static inline char* align_up(char* p, size_t a) {
  return (char*)(((uintptr_t)p + a - 1) & ~(a - 1));
}

extern "C" void kernel_launch(void* const* d_in, const int* in_sizes, int n_in,
                              void* d_out, int out_size, void* d_ws, size_t ws_size,
                              hipStream_t stream) {
  const float* x    = (const float*)d_in[0];
  const int*   ei   = (const int*)d_in[1];
  const int*   srcp = ei;
  const int*   dstp = ei + E;
  const int*   batch = (const int*)d_in[2];
  const float* eps1 = (const float*)d_in[3];
  const float* W1a  = (const float*)d_in[4];
  const float* b1a  = (const float*)d_in[5];
  const float* W1b  = (const float*)d_in[6];
  const float* b1b  = (const float*)d_in[7];
  const float* eps2 = (const float*)d_in[8];
  const float* W2a  = (const float*)d_in[9];
  const float* b2a  = (const float*)d_in[10];
  const float* W2b  = (const float*)d_in[11];
  const float* b2b  = (const float*)d_in[12];
  const float* Wlin = (const float*)d_in[13];
  const float* blin = (const float*)d_in[14];
  float* outp = (float*)d_out;

  char* p = (char*)d_ws;
  int* deg    = (int*)p;             p = align_up(p + (size_t)N * 4, 256);
  int* rowptr = (int*)p;             p = align_up(p + (size_t)(N + 1) * 4, 256);
  int* cur    = (int*)p;             p = align_up(p + (size_t)N * 4, 256);
  int* csre   = (int*)p;             p = align_up(p + (size_t)E * 4, 256);
  float* bufA = (float*)p;           p = align_up(p + (size_t)N * IN * 4, 256);
  float* bufB = (float*)p;           p = align_up(p + (size_t)N * H * 4, 256);
  float* bufC = (float*)p;           p = align_up(p + (size_t)N * H * 4, 256);
  float* pooled = (float*)p;         p = align_up(p + (size_t)G * H * 4, 256);

  hipMemsetAsync(deg, 0, (size_t)N * 4, stream);

  const int eblocks = (E + 255) / 256;
  deg_kernel<<<eblocks, 256, 0, stream>>>(dstp, deg);
  scan_kernel<<<1, 1024, 0, stream>>>(deg, rowptr, cur);
  fill_kernel<<<eblocks, 256, 0, stream>>>(srcp, dstp, cur, csre);

  const dim3 ggrid((N + 63) / 64, 4);

  // layer 1
  agg_kernel<IN><<<N, IN, 0, stream>>>(x, rowptr, csre, eps1, bufA);
  gemm_kernel<IN, true><<<ggrid, 256, 0, stream>>>(bufA, W1a, b1a, bufB, N);
  gemm_kernel<H, true><<<ggrid, 256, 0, stream>>>(bufB, W1b, b1b, bufC, N);  // bufC = h1

  // layer 2
  agg_kernel<H><<<N, H, 0, stream>>>(bufC, rowptr, csre, eps2, bufB);
  gemm_kernel<H, true><<<ggrid, 256, 0, stream>>>(bufB, W2a, b2a, bufC, N);
  gemm_kernel<H, false><<<ggrid, 256, 0, stream>>>(bufC, W2b, b2b, bufB, N);  // bufB = h2

  // pool + classify
  pool_kernel<<<G, H, 0, stream>>>(bufB, batch, pooled);
  final_kernel<<<G, 64, 0, stream>>>(pooled, Wlin, blin, outp);
}

// Round 2
// 441.677 us; speedup vs baseline: 2.0661x; 2.0661x over previous
//
#include <hip/hip_runtime.h>
#include <math.h>
#include <stdint.h>

constexpr int N   = 50000;
constexpr int E   = 800000;
constexpr int IN  = 128;
constexpr int H   = 256;
constexpr int OUT = 10;
constexpr int G   = 512;

typedef __bf16 bf16x8 __attribute__((ext_vector_type(8)));
typedef float  f32x4  __attribute__((ext_vector_type(4)));

__device__ __forceinline__ float blo(unsigned v) { return __uint_as_float(v << 16); }
__device__ __forceinline__ float bhi(unsigned v) { return __uint_as_float(v & 0xffff0000u); }
__device__ __forceinline__ unsigned short f2b(float f) {
  unsigned u = __float_as_uint(f);
  u += 0x7fffu + ((u >> 16) & 1u);   // round-to-nearest-even (no NaNs in this net)
  return (unsigned short)(u >> 16);
}
__device__ __forceinline__ unsigned packb(float lo, float hi) {
  return (unsigned)f2b(lo) | ((unsigned)f2b(hi) << 16);
}

// ---------------- CSR build ----------------

__global__ void deg_kernel(const int* __restrict__ dst, int* __restrict__ deg) {
  int e = blockIdx.x * blockDim.x + threadIdx.x;
  if (e < E) atomicAdd(&deg[dst[e]], 1);
}

constexpr int NCH = (N + 255) / 256;  // 196 chunks

__global__ void chunk_sum_kernel(const int* __restrict__ deg, int* __restrict__ csum) {
  __shared__ int red[256];
  int t = threadIdx.x;
  int i = blockIdx.x * 256 + t;
  red[t] = (i < N) ? deg[i] : 0;
  __syncthreads();
  for (int off = 128; off > 0; off >>= 1) {
    if (t < off) red[t] += red[t + off];
    __syncthreads();
  }
  if (t == 0) csum[blockIdx.x] = red[0];
}

__global__ void scan_chunks_kernel(int* __restrict__ csum, int* __restrict__ rowptr) {
  __shared__ int buf[256];
  int t = threadIdx.x;
  int v = (t < NCH) ? csum[t] : 0;
  buf[t] = v;
  __syncthreads();
  for (int off = 1; off < 256; off <<= 1) {
    int add = (t >= off) ? buf[t - off] : 0;
    __syncthreads();
    buf[t] += add;
    __syncthreads();
  }
  if (t < NCH) csum[t] = buf[t] - v;  // exclusive
  if (t == 0) rowptr[N] = E;
}

__global__ void scan_final_kernel(const int* __restrict__ deg, const int* __restrict__ csum,
                                  int* __restrict__ rowptr, int* __restrict__ cur) {
  __shared__ int buf[256];
  int t = threadIdx.x;
  int i = blockIdx.x * 256 + t;
  int v = (i < N) ? deg[i] : 0;
  buf[t] = v;
  __syncthreads();
  for (int off = 1; off < 256; off <<= 1) {
    int add = (t >= off) ? buf[t - off] : 0;
    __syncthreads();
    buf[t] += add;
    __syncthreads();
  }
  int excl = buf[t] - v + csum[blockIdx.x];
  if (i < N) { rowptr[i] = excl; cur[i] = excl; }
}

__global__ void fill_kernel(const int* __restrict__ src, const int* __restrict__ dst,
                            int* __restrict__ cur, int* __restrict__ csre) {
  int e = blockIdx.x * blockDim.x + threadIdx.x;
  if (e >= E) return;
  int pos = atomicAdd(&cur[dst[e]], 1);
  csre[pos] = src[e];
}

// ---------------- fp32 -> bf16 conversions ----------------

__global__ void conv_bf16_kernel(const float* __restrict__ in, unsigned short* __restrict__ out,
                                 int n4) {
  int id = blockIdx.x * blockDim.x + threadIdx.x;
  if (id >= n4) return;
  float4 v = ((const float4*)in)[id];
  ((uint2*)out)[id] = make_uint2(packb(v.x, v.y), packb(v.z, v.w));
}

// Wt[n][k] = bf16(W[k][n]); M = 256 output cols, K template (pow2)
template <int K>
__global__ void convT_kernel(const float* __restrict__ W, unsigned short* __restrict__ Wt) {
  int id = blockIdx.x * blockDim.x + threadIdx.x;
  if (id >= 256 * K) return;
  int n = id / K, k = id & (K - 1);
  Wt[id] = f2b(W[k * 256 + n]);
}

// ---------------- gather aggregation (bf16): out[i] = (1+eps)*in[i] + sum_{j in N(i)} in[j] ----------------
// block = 64 threads, one block per node; V = D/64 bf16 per thread.

template <int D>
__global__ void agg_bf16_kernel(const unsigned short* __restrict__ in,
                                const int* __restrict__ rowptr, const int* __restrict__ csre,
                                const float* __restrict__ epsp, unsigned short* __restrict__ out) {
  constexpr int V = D / 64;  // 2 or 4
  int i = blockIdx.x;
  int t = threadIdx.x;
  int s = rowptr[i], e = rowptr[i + 1];
  float sc = 1.0f + epsp[0];
  if constexpr (V == 2) {
    float a0 = 0.f, a1 = 0.f;
    const unsigned* base = (const unsigned*)in;
    for (int j = s; j < e; ++j) {
      unsigned v = base[(size_t)csre[j] * (D / 2) + t];
      a0 += blo(v); a1 += bhi(v);
    }
    unsigned sv = base[(size_t)i * (D / 2) + t];
    a0 += sc * blo(sv); a1 += sc * bhi(sv);
    ((unsigned*)out)[(size_t)i * (D / 2) + t] = packb(a0, a1);
  } else {
    float a0 = 0.f, a1 = 0.f, a2 = 0.f, a3 = 0.f;
    const uint2* base = (const uint2*)in;
    for (int j = s; j < e; ++j) {
      uint2 v = base[(size_t)csre[j] * (D / 4) + t];
      a0 += blo(v.x); a1 += bhi(v.x); a2 += blo(v.y); a3 += bhi(v.y);
    }
    uint2 sv = base[(size_t)i * (D / 4) + t];
    a0 += sc * blo(sv.x); a1 += sc * bhi(sv.x); a2 += sc * blo(sv.y); a3 += sc * bhi(sv.y);
    ((uint2*)out)[(size_t)i * (D / 4) + t] = make_uint2(packb(a0, a1), packb(a2, a3));
  }
}

// ---------------- bf16 MFMA GEMM: out[N][256] = act(A[N][K] @ W[K][256] + b) ----------------
// A: row-major bf16 [Nrows][K]. Bt: pre-transposed bf16 [256][K] (Bt[n][k] = W[k][n]).
// Tile 128x128, BK=32, block = 256 threads = 4 waves (2x2 of 64x64 per wave),
// per wave 4x4 grid of 16x16x32 MFMAs. LDS k-stride padded to 40 (conflict-free).

template <int K, bool RELU>
__global__ __launch_bounds__(256, 2) void gemm_bf16_kernel(const unsigned short* __restrict__ A,
                                                           const unsigned short* __restrict__ Bt,
                                                           const float* __restrict__ bias,
                                                           unsigned short* __restrict__ out,
                                                           int Nrows) {
  constexpr int M = 256;
  constexpr int LDK = 40;
  __shared__ __align__(16) unsigned short As[128 * LDK];
  __shared__ __align__(16) unsigned short Bs[128 * LDK];
  const int tid  = threadIdx.x;
  const int r0   = blockIdx.x * 128;
  const int c0   = blockIdx.y * 128;
  const int wave = tid >> 6, lane = tid & 63;
  const int quad = lane >> 4, l15 = lane & 15;
  const int wrow = (wave >> 1) * 64, wcol = (wave & 1) * 64;
  const int srow = tid >> 2;        // 0..63
  const int sk8  = (tid & 3) * 8;   // 0,8,16,24

  f32x4 acc[4][4];
#pragma unroll
  for (int i = 0; i < 4; ++i)
#pragma unroll
    for (int j = 0; j < 4; ++j) acc[i][j] = (f32x4){0.f, 0.f, 0.f, 0.f};

  for (int k0 = 0; k0 < K; k0 += 32) {
    // stage A (rows srow, srow+64) with zero-fill for OOB rows
    {
      int row = srow, grow = r0 + row;
      uint4 v = make_uint4(0u, 0u, 0u, 0u);
      if (grow < Nrows) v = *(const uint4*)(A + (size_t)grow * K + k0 + sk8);
      *(uint4*)(As + row * LDK + sk8) = v;
      row += 64; grow = r0 + row;
      uint4 w = make_uint4(0u, 0u, 0u, 0u);
      if (grow < Nrows) w = *(const uint4*)(A + (size_t)grow * K + k0 + sk8);
      *(uint4*)(As + row * LDK + sk8) = w;
      // stage B (always in-range: c0+row < 256)
      *(uint4*)(Bs + srow * LDK + sk8) =
          *(const uint4*)(Bt + (size_t)(c0 + srow) * K + k0 + sk8);
      *(uint4*)(Bs + (srow + 64) * LDK + sk8) =
          *(const uint4*)(Bt + (size_t)(c0 + srow + 64) * K + k0 + sk8);
    }
    __syncthreads();
    bf16x8 af[4], bfr[4];
#pragma unroll
    for (int mt = 0; mt < 4; ++mt)
      af[mt] = *(const bf16x8*)(As + (wrow + mt * 16 + l15) * LDK + quad * 8);
#pragma unroll
    for (int nt = 0; nt < 4; ++nt)
      bfr[nt] = *(const bf16x8*)(Bs + (wcol + nt * 16 + l15) * LDK + quad * 8);
#pragma unroll
    for (int mt = 0; mt < 4; ++mt)
#pragma unroll
      for (int nt = 0; nt < 4; ++nt)
        acc[mt][nt] = __builtin_amdgcn_mfma_f32_16x16x32_bf16(af[mt], bfr[nt], acc[mt][nt], 0, 0, 0);
    __syncthreads();
  }

  float bv[4];
#pragma unroll
  for (int nt = 0; nt < 4; ++nt) bv[nt] = bias[c0 + wcol + nt * 16 + l15];
#pragma unroll
  for (int mt = 0; mt < 4; ++mt) {
    int gr0 = r0 + wrow + mt * 16 + quad * 4;
#pragma unroll
    for (int i = 0; i < 4; ++i) {
      int grow = gr0 + i;
      if (grow >= Nrows) continue;
#pragma unroll
      for (int nt = 0; nt < 4; ++nt) {
        float v = acc[mt][nt][i] + bv[nt];
        if (RELU) v = fmaxf(v, 0.f);
        out[(size_t)grow * M + c0 + wcol + nt * 16 + l15] = f2b(v);
      }
    }
  }
}

// ---------------- per-graph mean pool (batch sorted), bf16 in / fp32 out ----------------

__global__ void pool_kernel(const unsigned short* __restrict__ h2, const int* __restrict__ batch,
                            float* __restrict__ pooled) {
  int g = blockIdx.x;
  int t = threadIdx.x;  // 128 threads, 2 cols each
  int lo = 0, hi = N;
  while (lo < hi) { int m = (lo + hi) >> 1; if (batch[m] < g) lo = m + 1; else hi = m; }
  int s = lo;
  lo = 0; hi = N;
  while (lo < hi) { int m = (lo + hi) >> 1; if (batch[m] < g + 1) lo = m + 1; else hi = m; }
  int e = lo;
  float a0 = 0.f, a1 = 0.f;
  const unsigned* base = (const unsigned*)h2;
  for (int n = s; n < e; ++n) {
    unsigned v = base[(size_t)n * (H / 2) + t];
    a0 += blo(v); a1 += bhi(v);
  }
  float inv = 1.0f / fmaxf((float)(e - s), 1.0f);
  pooled[(size_t)g * H + 2 * t]     = a0 * inv;
  pooled[(size_t)g * H + 2 * t + 1] = a1 * inv;
}

// ---------------- final linear + log_softmax (fp32) ----------------

__global__ void final_kernel(const float* __restrict__ pooled, const float* __restrict__ Wlin,
                             const float* __restrict__ blin, float* __restrict__ out) {
  int g = blockIdx.x;
  int t = threadIdx.x;  // 64
  __shared__ float sp[H];
  __shared__ float logits[OUT];
  for (int i = t; i < H; i += 64) sp[i] = pooled[(size_t)g * H + i];
  __syncthreads();
  if (t < OUT) {
    float acc = blin[t];
    for (int k = 0; k < H; ++k) acc = fmaf(sp[k], Wlin[k * OUT + t], acc);
    logits[t] = acc;
  }
  __syncthreads();
  if (t == 0) {
    float m = -INFINITY;
    for (int j = 0; j < OUT; ++j) m = fmaxf(m, logits[j]);
    float s = 0.f;
    for (int j = 0; j < OUT; ++j) s += expf(logits[j] - m);
    float ls = logf(s);
    for (int j = 0; j < OUT; ++j) out[(size_t)g * OUT + j] = logits[j] - m - ls;
  }
}

// ---------------- launch ----------------

static inline char* align_up(char* p, size_t a) {
  return (char*)(((uintptr_t)p + a - 1) & ~(a - 1));
}

extern "C" void kernel_launch(void* const* d_in, const int* in_sizes, int n_in,
                              void* d_out, int out_size, void* d_ws, size_t ws_size,
                              hipStream_t stream) {
  const float* x    = (const float*)d_in[0];
  const int*   ei   = (const int*)d_in[1];
  const int*   srcp = ei;
  const int*   dstp = ei + E;
  const int*   batch = (const int*)d_in[2];
  const float* eps1 = (const float*)d_in[3];
  const float* W1a  = (const float*)d_in[4];
  const float* b1a  = (const float*)d_in[5];
  const float* W1b  = (const float*)d_in[6];
  const float* b1b  = (const float*)d_in[7];
  const float* eps2 = (const float*)d_in[8];
  const float* W2a  = (const float*)d_in[9];
  const float* b2a  = (const float*)d_in[10];
  const float* W2b  = (const float*)d_in[11];
  const float* b2b  = (const float*)d_in[12];
  const float* Wlin = (const float*)d_in[13];
  const float* blin = (const float*)d_in[14];
  float* outp = (float*)d_out;

  char* p = (char*)d_ws;
  int* deg    = (int*)p;              p = align_up(p + (size_t)N * 4, 256);
  int* rowptr = (int*)p;              p = align_up(p + (size_t)(N + 1) * 4, 256);
  int* cur    = (int*)p;              p = align_up(p + (size_t)N * 4, 256);
  int* csum   = (int*)p;              p = align_up(p + (size_t)256 * 4, 256);
  int* csre   = (int*)p;              p = align_up(p + (size_t)E * 4, 256);
  unsigned short* xb   = (unsigned short*)p;  p = align_up(p + (size_t)N * IN * 2, 256);
  unsigned short* a1   = (unsigned short*)p;  p = align_up(p + (size_t)N * IN * 2, 256);
  unsigned short* B1   = (unsigned short*)p;  p = align_up(p + (size_t)N * H * 2, 256);
  unsigned short* B2   = (unsigned short*)p;  p = align_up(p + (size_t)N * H * 2, 256);
  unsigned short* B3   = (unsigned short*)p;  p = align_up(p + (size_t)N * H * 2, 256);
  unsigned short* Wt1a = (unsigned short*)p;  p = align_up(p + (size_t)H * IN * 2, 256);
  unsigned short* Wt1b = (unsigned short*)p;  p = align_up(p + (size_t)H * H * 2, 256);
  unsigned short* Wt2a = (unsigned short*)p;  p = align_up(p + (size_t)H * H * 2, 256);
  unsigned short* Wt2b = (unsigned short*)p;  p = align_up(p + (size_t)H * H * 2, 256);
  float* pooled = (float*)p;          p = align_up(p + (size_t)G * H * 4, 256);

  hipMemsetAsync(deg, 0, (size_t)N * 4, stream);

  const int eblocks = (E + 255) / 256;
  deg_kernel<<<eblocks, 256, 0, stream>>>(dstp, deg);
  chunk_sum_kernel<<<NCH, 256, 0, stream>>>(deg, csum);
  scan_chunks_kernel<<<1, 256, 0, stream>>>(csum, rowptr);
  scan_final_kernel<<<NCH, 256, 0, stream>>>(deg, csum, rowptr, cur);
  fill_kernel<<<eblocks, 256, 0, stream>>>(srcp, dstp, cur, csre);

  // conversions
  conv_bf16_kernel<<<(N * IN / 4 + 255) / 256, 256, 0, stream>>>(x, xb, N * IN / 4);
  convT_kernel<IN><<<(256 * IN + 255) / 256, 256, 0, stream>>>(W1a, Wt1a);
  convT_kernel<H><<<(256 * H + 255) / 256, 256, 0, stream>>>(W1b, Wt1b);
  convT_kernel<H><<<(256 * H + 255) / 256, 256, 0, stream>>>(W2a, Wt2a);
  convT_kernel<H><<<(256 * H + 255) / 256, 256, 0, stream>>>(W2b, Wt2b);

  const dim3 ggrid((N + 127) / 128, 2);

  // layer 1
  agg_bf16_kernel<IN><<<N, 64, 0, stream>>>(xb, rowptr, csre, eps1, a1);
  gemm_bf16_kernel<IN, true><<<ggrid, 256, 0, stream>>>(a1, Wt1a, b1a, B1, N);
  gemm_bf16_kernel<H, true><<<ggrid, 256, 0, stream>>>(B1, Wt1b, b1b, B2, N);  // B2 = h1

  // layer 2
  agg_bf16_kernel<H><<<N, 64, 0, stream>>>(B2, rowptr, csre, eps2, B3);
  gemm_bf16_kernel<H, true><<<ggrid, 256, 0, stream>>>(B3, Wt2a, b2a, B1, N);
  gemm_bf16_kernel<H, false><<<ggrid, 256, 0, stream>>>(B1, Wt2b, b2b, B2, N);  // B2 = h2

  // pool + classify
  pool_kernel<<<G, 128, 0, stream>>>(B2, batch, pooled);
  final_kernel<<<G, 64, 0, stream>>>(pooled, Wlin, blin, outp);
}

// Round 3
// 401.463 us; speedup vs baseline: 2.2730x; 1.1002x over previous
//
#include <hip/hip_runtime.h>
#include <math.h>
#include <stdint.h>

constexpr int N   = 50000;
constexpr int E   = 800000;
constexpr int IN  = 128;
constexpr int H   = 256;
constexpr int OUT = 10;
constexpr int G   = 512;

typedef __bf16 bf16x8 __attribute__((ext_vector_type(8)));
typedef float  f32x4  __attribute__((ext_vector_type(4)));

__device__ __forceinline__ float blo(unsigned v) { return __uint_as_float(v << 16); }
__device__ __forceinline__ float bhi(unsigned v) { return __uint_as_float(v & 0xffff0000u); }
__device__ __forceinline__ unsigned short f2b(float f) {
  unsigned u = __float_as_uint(f);
  u += 0x7fffu + ((u >> 16) & 1u);   // round-to-nearest-even (no NaNs in this net)
  return (unsigned short)(u >> 16);
}
__device__ __forceinline__ unsigned packb(float lo, float hi) {
  return (unsigned)f2b(lo) | ((unsigned)f2b(hi) << 16);
}

// ---------------- CSR build ----------------

__global__ void deg_kernel(const int* __restrict__ dst, int* __restrict__ deg) {
  int e = blockIdx.x * blockDim.x + threadIdx.x;
  if (e < E) atomicAdd(&deg[dst[e]], 1);
}

constexpr int NCH = (N + 255) / 256;  // 196 chunks

__global__ void chunk_sum_kernel(const int* __restrict__ deg, int* __restrict__ csum) {
  __shared__ int red[256];
  int t = threadIdx.x;
  int i = blockIdx.x * 256 + t;
  red[t] = (i < N) ? deg[i] : 0;
  __syncthreads();
  for (int off = 128; off > 0; off >>= 1) {
    if (t < off) red[t] += red[t + off];
    __syncthreads();
  }
  if (t == 0) csum[blockIdx.x] = red[0];
}

__global__ void scan_chunks_kernel(int* __restrict__ csum, int* __restrict__ rowptr) {
  __shared__ int buf[256];
  int t = threadIdx.x;
  int v = (t < NCH) ? csum[t] : 0;
  buf[t] = v;
  __syncthreads();
  for (int off = 1; off < 256; off <<= 1) {
    int add = (t >= off) ? buf[t - off] : 0;
    __syncthreads();
    buf[t] += add;
    __syncthreads();
  }
  if (t < NCH) csum[t] = buf[t] - v;  // exclusive
  if (t == 0) rowptr[N] = E;
}

__global__ void scan_final_kernel(const int* __restrict__ deg, const int* __restrict__ csum,
                                  int* __restrict__ rowptr, int* __restrict__ cur) {
  __shared__ int buf[256];
  int t = threadIdx.x;
  int i = blockIdx.x * 256 + t;
  int v = (i < N) ? deg[i] : 0;
  buf[t] = v;
  __syncthreads();
  for (int off = 1; off < 256; off <<= 1) {
    int add = (t >= off) ? buf[t - off] : 0;
    __syncthreads();
    buf[t] += add;
    __syncthreads();
  }
  int excl = buf[t] - v + csum[blockIdx.x];
  if (i < N) { rowptr[i] = excl; cur[i] = excl; }
}

__global__ void fill_kernel(const int* __restrict__ src, const int* __restrict__ dst,
                            int* __restrict__ cur, int* __restrict__ csre) {
  int e = blockIdx.x * blockDim.x + threadIdx.x;
  if (e >= E) return;
  int pos = atomicAdd(&cur[dst[e]], 1);
  csre[pos] = src[e];
}

// ---------------- fused fp32->bf16 conversions (x + 4 weight transposes) ----------------
// grid sections: [0,6250) x-conv float4; [6250,6378) Wt1a; then 3 x 256 blocks for H x H.

constexpr int XB_BLOCKS  = (N * IN / 4) / 256;      // 6250 (exact)
constexpr int W1A_BLOCKS = (256 * IN) / 256;        // 128
constexpr int WH_BLOCKS  = (256 * H) / 256;         // 256

__global__ void prep_kernel(const float* __restrict__ x, unsigned short* __restrict__ xb,
                            const float* __restrict__ W1a, unsigned short* __restrict__ Wt1a,
                            const float* __restrict__ W1b, unsigned short* __restrict__ Wt1b,
                            const float* __restrict__ W2a, unsigned short* __restrict__ Wt2a,
                            const float* __restrict__ W2b, unsigned short* __restrict__ Wt2b) {
  int b = blockIdx.x;
  int t = threadIdx.x;
  if (b < XB_BLOCKS) {
    int id = b * 256 + t;
    float4 v = ((const float4*)x)[id];
    ((uint2*)xb)[id] = make_uint2(packb(v.x, v.y), packb(v.z, v.w));
    return;
  }
  b -= XB_BLOCKS;
  if (b < W1A_BLOCKS) {
    int id = b * 256 + t;               // id = n*128 + k
    int n = id >> 7, k = id & 127;
    Wt1a[id] = f2b(W1a[k * 256 + n]);
    return;
  }
  b -= W1A_BLOCKS;
  const float* Ws;
  unsigned short* Wd;
  if (b < WH_BLOCKS)            { Ws = W1b; Wd = Wt1b; }
  else if (b < 2 * WH_BLOCKS)   { Ws = W2a; Wd = Wt2a; b -= WH_BLOCKS; }
  else                          { Ws = W2b; Wd = Wt2b; b -= 2 * WH_BLOCKS; }
  int id = b * 256 + t;                 // id = n*256 + k
  int n = id >> 8, k = id & 255;
  Wd[id] = f2b(Ws[k * 256 + n]);
}

// ---------------- gather aggregation (bf16): out[i] = (1+eps)*in[i] + sum_{j in N(i)} in[j] ----
// block = 64 threads (one wave per node). Neighbor indices preloaded in chunks of 8 so
// 8 row-gathers are in flight per lane (latency-bound -> MLP).

template <int D>
__global__ __launch_bounds__(64) void agg_bf16_kernel(const unsigned short* __restrict__ in,
                                const int* __restrict__ rowptr, const int* __restrict__ csre,
                                const float* __restrict__ epsp, unsigned short* __restrict__ out) {
  int i = blockIdx.x;
  int t = threadIdx.x;
  int s = rowptr[i], e = rowptr[i + 1];
  float sc = 1.0f + epsp[0];
  if constexpr (D == 128) {
    const unsigned* base = (const unsigned*)in;
    float a0 = 0.f, a1 = 0.f;
    int j = s;
    for (; j + 8 <= e; j += 8) {
      int idx[8];
#pragma unroll
      for (int u = 0; u < 8; ++u) idx[u] = csre[j + u];
      unsigned v[8];
#pragma unroll
      for (int u = 0; u < 8; ++u) v[u] = base[(size_t)idx[u] * 64 + t];
#pragma unroll
      for (int u = 0; u < 8; ++u) { a0 += blo(v[u]); a1 += bhi(v[u]); }
    }
    for (; j < e; ++j) {
      unsigned v = base[(size_t)csre[j] * 64 + t];
      a0 += blo(v); a1 += bhi(v);
    }
    unsigned sv = base[(size_t)i * 64 + t];
    a0 += sc * blo(sv); a1 += sc * bhi(sv);
    ((unsigned*)out)[(size_t)i * 64 + t] = packb(a0, a1);
  } else {
    const uint2* base = (const uint2*)in;
    float a0 = 0.f, a1 = 0.f, a2 = 0.f, a3 = 0.f;
    int j = s;
    for (; j + 8 <= e; j += 8) {
      int idx[8];
#pragma unroll
      for (int u = 0; u < 8; ++u) idx[u] = csre[j + u];
      uint2 v[8];
#pragma unroll
      for (int u = 0; u < 8; ++u) v[u] = base[(size_t)idx[u] * 64 + t];
#pragma unroll
      for (int u = 0; u < 8; ++u) {
        a0 += blo(v[u].x); a1 += bhi(v[u].x); a2 += blo(v[u].y); a3 += bhi(v[u].y);
      }
    }
    for (; j < e; ++j) {
      uint2 v = base[(size_t)csre[j] * 64 + t];
      a0 += blo(v.x); a1 += bhi(v.x); a2 += blo(v.y); a3 += bhi(v.y);
    }
    uint2 sv = base[(size_t)i * 64 + t];
    a0 += sc * blo(sv.x); a1 += sc * bhi(sv.x); a2 += sc * blo(sv.y); a3 += sc * bhi(sv.y);
    ((uint2*)out)[(size_t)i * 64 + t] = make_uint2(packb(a0, a1), packb(a2, a3));
  }
}

// ---------------- bf16 MFMA GEMM: out[N][256] = act(A[N][K] @ W[K][256] + b) ----------------
// A: row-major bf16 [Nrows][K]. Bt: pre-transposed bf16 [256][K] (Bt[n][k] = W[k][n]).
// Tile 128x128, BK=32, block = 256 threads = 4 waves (2x2 of 64x64 per wave),
// per wave 4x4 grid of 16x16x32 MFMAs. LDS k-stride padded to 40 (conflict-free).

template <int K, bool RELU>
__global__ __launch_bounds__(256, 2) void gemm_bf16_kernel(const unsigned short* __restrict__ A,
                                                           const unsigned short* __restrict__ Bt,
                                                           const float* __restrict__ bias,
                                                           unsigned short* __restrict__ out,
                                                           int Nrows) {
  constexpr int M = 256;
  constexpr int LDK = 40;
  __shared__ __align__(16) unsigned short As[128 * LDK];
  __shared__ __align__(16) unsigned short Bs[128 * LDK];
  const int tid  = threadIdx.x;
  const int r0   = blockIdx.x * 128;
  const int c0   = blockIdx.y * 128;
  const int wave = tid >> 6, lane = tid & 63;
  const int quad = lane >> 4, l15 = lane & 15;
  const int wrow = (wave >> 1) * 64, wcol = (wave & 1) * 64;
  const int srow = tid >> 2;        // 0..63
  const int sk8  = (tid & 3) * 8;   // 0,8,16,24

  f32x4 acc[4][4];
#pragma unroll
  for (int i = 0; i < 4; ++i)
#pragma unroll
    for (int j = 0; j < 4; ++j) acc[i][j] = (f32x4){0.f, 0.f, 0.f, 0.f};

  for (int k0 = 0; k0 < K; k0 += 32) {
    {
      int row = srow, grow = r0 + row;
      uint4 v = make_uint4(0u, 0u, 0u, 0u);
      if (grow < Nrows) v = *(const uint4*)(A + (size_t)grow * K + k0 + sk8);
      *(uint4*)(As + row * LDK + sk8) = v;
      row += 64; grow = r0 + row;
      uint4 w = make_uint4(0u, 0u, 0u, 0u);
      if (grow < Nrows) w = *(const uint4*)(A + (size_t)grow * K + k0 + sk8);
      *(uint4*)(As + row * LDK + sk8) = w;
      *(uint4*)(Bs + srow * LDK + sk8) =
          *(const uint4*)(Bt + (size_t)(c0 + srow) * K + k0 + sk8);
      *(uint4*)(Bs + (srow + 64) * LDK + sk8) =
          *(const uint4*)(Bt + (size_t)(c0 + srow + 64) * K + k0 + sk8);
    }
    __syncthreads();
    bf16x8 af[4], bfr[4];
#pragma unroll
    for (int mt = 0; mt < 4; ++mt)
      af[mt] = *(const bf16x8*)(As + (wrow + mt * 16 + l15) * LDK + quad * 8);
#pragma unroll
    for (int nt = 0; nt < 4; ++nt)
      bfr[nt] = *(const bf16x8*)(Bs + (wcol + nt * 16 + l15) * LDK + quad * 8);
#pragma unroll
    for (int mt = 0; mt < 4; ++mt)
#pragma unroll
      for (int nt = 0; nt < 4; ++nt)
        acc[mt][nt] = __builtin_amdgcn_mfma_f32_16x16x32_bf16(af[mt], bfr[nt], acc[mt][nt], 0, 0, 0);
    __syncthreads();
  }

  float bv[4];
#pragma unroll
  for (int nt = 0; nt < 4; ++nt) bv[nt] = bias[c0 + wcol + nt * 16 + l15];
#pragma unroll
  for (int mt = 0; mt < 4; ++mt) {
    int gr0 = r0 + wrow + mt * 16 + quad * 4;
#pragma unroll
    for (int i = 0; i < 4; ++i) {
      int grow = gr0 + i;
      if (grow >= Nrows) continue;
#pragma unroll
      for (int nt = 0; nt < 4; ++nt) {
        float v = acc[mt][nt][i] + bv[nt];
        if (RELU) v = fmaxf(v, 0.f);
        out[(size_t)grow * M + c0 + wcol + nt * 16 + l15] = f2b(v);
      }
    }
  }
}

// ---------------- per-graph mean pool (batch sorted), bf16 in / fp32 out ----------------

__global__ void pool_kernel(const unsigned short* __restrict__ h2, const int* __restrict__ batch,
                            float* __restrict__ pooled) {
  int g = blockIdx.x;
  int t = threadIdx.x;  // 128 threads, 2 cols each
  int lo = 0, hi = N;
  while (lo < hi) { int m = (lo + hi) >> 1; if (batch[m] < g) lo = m + 1; else hi = m; }
  int s = lo;
  lo = 0; hi = N;
  while (lo < hi) { int m = (lo + hi) >> 1; if (batch[m] < g + 1) lo = m + 1; else hi = m; }
  int e = lo;
  float a0 = 0.f, a1 = 0.f;
  const unsigned* base = (const unsigned*)h2;
  int n = s;
  for (; n + 4 <= e; n += 4) {
    unsigned v0 = base[(size_t)(n + 0) * (H / 2) + t];
    unsigned v1 = base[(size_t)(n + 1) * (H / 2) + t];
    unsigned v2 = base[(size_t)(n + 2) * (H / 2) + t];
    unsigned v3 = base[(size_t)(n + 3) * (H / 2) + t];
    a0 += blo(v0) + blo(v1) + blo(v2) + blo(v3);
    a1 += bhi(v0) + bhi(v1) + bhi(v2) + bhi(v3);
  }
  for (; n < e; ++n) {
    unsigned v = base[(size_t)n * (H / 2) + t];
    a0 += blo(v); a1 += bhi(v);
  }
  float inv = 1.0f / fmaxf((float)(e - s), 1.0f);
  pooled[(size_t)g * H + 2 * t]     = a0 * inv;
  pooled[(size_t)g * H + 2 * t + 1] = a1 * inv;
}

// ---------------- final linear + log_softmax (fp32) ----------------

__global__ void final_kernel(const float* __restrict__ pooled, const float* __restrict__ Wlin,
                             const float* __restrict__ blin, float* __restrict__ out) {
  int g = blockIdx.x;
  int t = threadIdx.x;  // 64
  __shared__ float sp[H];
  __shared__ float logits[OUT];
  for (int i = t; i < H; i += 64) sp[i] = pooled[(size_t)g * H + i];
  __syncthreads();
  if (t < OUT) {
    float acc = blin[t];
    for (int k = 0; k < H; ++k) acc = fmaf(sp[k], Wlin[k * OUT + t], acc);
    logits[t] = acc;
  }
  __syncthreads();
  if (t == 0) {
    float m = -INFINITY;
    for (int j = 0; j < OUT; ++j) m = fmaxf(m, logits[j]);
    float s = 0.f;
    for (int j = 0; j < OUT; ++j) s += expf(logits[j] - m);
    float ls = logf(s);
    for (int j = 0; j < OUT; ++j) out[(size_t)g * OUT + j] = logits[j] - m - ls;
  }
}

// ---------------- launch ----------------

static inline char* align_up(char* p, size_t a) {
  return (char*)(((uintptr_t)p + a - 1) & ~(a - 1));
}

extern "C" void kernel_launch(void* const* d_in, const int* in_sizes, int n_in,
                              void* d_out, int out_size, void* d_ws, size_t ws_size,
                              hipStream_t stream) {
  const float* x    = (const float*)d_in[0];
  const int*   ei   = (const int*)d_in[1];
  const int*   srcp = ei;
  const int*   dstp = ei + E;
  const int*   batch = (const int*)d_in[2];
  const float* eps1 = (const float*)d_in[3];
  const float* W1a  = (const float*)d_in[4];
  const float* b1a  = (const float*)d_in[5];
  const float* W1b  = (const float*)d_in[6];
  const float* b1b  = (const float*)d_in[7];
  const float* eps2 = (const float*)d_in[8];
  const float* W2a  = (const float*)d_in[9];
  const float* b2a  = (const float*)d_in[10];
  const float* W2b  = (const float*)d_in[11];
  const float* b2b  = (const float*)d_in[12];
  const float* Wlin = (const float*)d_in[13];
  const float* blin = (const float*)d_in[14];
  float* outp = (float*)d_out;

  char* p = (char*)d_ws;
  int* deg    = (int*)p;              p = align_up(p + (size_t)N * 4, 256);
  int* rowptr = (int*)p;              p = align_up(p + (size_t)(N + 1) * 4, 256);
  int* cur    = (int*)p;              p = align_up(p + (size_t)N * 4, 256);
  int* csum   = (int*)p;              p = align_up(p + (size_t)256 * 4, 256);
  int* csre   = (int*)p;              p = align_up(p + (size_t)E * 4, 256);
  unsigned short* xb   = (unsigned short*)p;  p = align_up(p + (size_t)N * IN * 2, 256);
  unsigned short* a1   = (unsigned short*)p;  p = align_up(p + (size_t)N * IN * 2, 256);
  unsigned short* B1   = (unsigned short*)p;  p = align_up(p + (size_t)N * H * 2, 256);
  unsigned short* B2   = (unsigned short*)p;  p = align_up(p + (size_t)N * H * 2, 256);
  unsigned short* B3   = (unsigned short*)p;  p = align_up(p + (size_t)N * H * 2, 256);
  unsigned short* Wt1a = (unsigned short*)p;  p = align_up(p + (size_t)H * IN * 2, 256);
  unsigned short* Wt1b = (unsigned short*)p;  p = align_up(p + (size_t)H * H * 2, 256);
  unsigned short* Wt2a = (unsigned short*)p;  p = align_up(p + (size_t)H * H * 2, 256);
  unsigned short* Wt2b = (unsigned short*)p;  p = align_up(p + (size_t)H * H * 2, 256);
  float* pooled = (float*)p;          p = align_up(p + (size_t)G * H * 4, 256);

  hipMemsetAsync(deg, 0, (size_t)N * 4, stream);

  const int eblocks = (E + 255) / 256;
  deg_kernel<<<eblocks, 256, 0, stream>>>(dstp, deg);
  chunk_sum_kernel<<<NCH, 256, 0, stream>>>(deg, csum);
  scan_chunks_kernel<<<1, 256, 0, stream>>>(csum, rowptr);
  scan_final_kernel<<<NCH, 256, 0, stream>>>(deg, csum, rowptr, cur);
  fill_kernel<<<eblocks, 256, 0, stream>>>(srcp, dstp, cur, csre);

  prep_kernel<<<XB_BLOCKS + W1A_BLOCKS + 3 * WH_BLOCKS, 256, 0, stream>>>(
      x, xb, W1a, Wt1a, W1b, Wt1b, W2a, Wt2a, W2b, Wt2b);

  const dim3 ggrid((N + 127) / 128, 2);

  // layer 1
  agg_bf16_kernel<IN><<<N, 64, 0, stream>>>(xb, rowptr, csre, eps1, a1);
  gemm_bf16_kernel<IN, true><<<ggrid, 256, 0, stream>>>(a1, Wt1a, b1a, B1, N);
  gemm_bf16_kernel<H, true><<<ggrid, 256, 0, stream>>>(B1, Wt1b, b1b, B2, N);  // B2 = h1

  // layer 2
  agg_bf16_kernel<H><<<N, 64, 0, stream>>>(B2, rowptr, csre, eps2, B3);
  gemm_bf16_kernel<H, true><<<ggrid, 256, 0, stream>>>(B3, Wt2a, b2a, B1, N);
  gemm_bf16_kernel<H, false><<<ggrid, 256, 0, stream>>>(B1, Wt2b, b2b, B2, N);  // B2 = h2

  // pool + classify
  pool_kernel<<<G, 128, 0, stream>>>(B2, batch, pooled);
  final_kernel<<<G, 64, 0, stream>>>(pooled, Wlin, blin, outp);
}